// Round 4
// baseline (2037.379 us; speedup 1.0000x reference)
//
#include <hip/hip_runtime.h>

// Problem constants (from reference)
#define N_A 100000
#define N_B 60000
#define N_C 40000
#define NTOT 200000   // N_A + N_B + N_C
#define NEDGE 3200000
#define D 64

#define NB 782        // ceil(NTOT / 256) destination buckets (256 nodes each)

// ---------------------------------------------------------------------------
// GEMM v2: Y[node0out + n] = act(X[n] @ W + b),  X:[Nn][K], W:[K][64]
// Block: 128 threads (2 waves), tile 128 nodes x 64 dims, thread = 8n x 8d.
// K-chunk 32. sF stored TRANSPOSED [k][n] (pad 132) so compute reads are
// b128 (2-way banks); staging lane-map makes the transpose writes
// conflict-free (bank = lane%32). Feat+W for chunk t+1 prefetched into
// registers during compute of chunk t (commit after barrier -> global
// latency hidden under 2048 FMAs). LDS 24.5 KB -> 6 blocks/CU.
// ---------------------------------------------------------------------------
template <int K, bool RELU>
__global__ __launch_bounds__(128) void gemm128_kernel(
    const float* __restrict__ X, const float* __restrict__ W,
    const float* __restrict__ bias, float* __restrict__ Y,
    int Nn, int node0out)
{
    __shared__ float sF[32][132];   // [k][n] transposed feat chunk
    __shared__ float sW[32 * 64];   // [k][d]

    const int tid = threadIdx.x;
    const int w   = tid >> 6;        // wave 0..1
    const int l   = tid & 63;
    const int l5  = l >> 5;
    const int l31 = l & 31;
    const int tn  = tid >> 3;        // 0..15 -> nodes tn*8..tn*8+7
    const int td  = tid & 7;         // dims td*8..td*8+7
    const int n0  = tn * 8;
    const int d0  = td * 8;
    const int bn  = blockIdx.x * 128;

    float  acc[8][8] = {};           // [n][d]
    float4 pf[8];                    // prefetched feat quads
    float4 pw[4];                    // prefetched W quads

    // staging map: p=0..7 -> node n = l31 + 32*(p&3), k-quad tk = l5 + 2*(p>>2) + 4*w
    // write bank = (16*tk + 4*c + n) % 32 = (16*l5 + l31 + const) % 32  -> 2-way max
#define LOAD_F(k0_)                                                          \
    _Pragma("unroll")                                                        \
    for (int p = 0; p < 8; ++p) {                                            \
        const int n  = l31 + 32 * (p & 3);                                   \
        const int tk = l5 + 2 * (p >> 2) + 4 * w;                            \
        const int gn = bn + n;                                               \
        pf[p] = (gn < Nn)                                                    \
            ? *(const float4*)(X + (long long)gn * K + (k0_) + tk * 4)       \
            : make_float4(0.f, 0.f, 0.f, 0.f);                               \
    }
#define LOAD_W(k0_)                                                          \
    {                                                                        \
        const float4* gw = (const float4*)(W + (long long)(k0_) * 64);       \
        _Pragma("unroll")                                                    \
        for (int c = 0; c < 4; ++c) pw[c] = gw[c * 128 + tid];               \
    }

    LOAD_F(0)
    LOAD_W(0)

    for (int k0 = 0; k0 < K; k0 += 32) {
        __syncthreads();             // previous compute done reading LDS
        // commit staged registers to LDS
#pragma unroll
        for (int p = 0; p < 8; ++p) {
            const int n  = l31 + 32 * (p & 3);
            const int tk = l5 + 2 * (p >> 2) + 4 * w;
            sF[tk * 4 + 0][n] = pf[p].x;
            sF[tk * 4 + 1][n] = pf[p].y;
            sF[tk * 4 + 2][n] = pf[p].z;
            sF[tk * 4 + 3][n] = pf[p].w;
        }
#pragma unroll
        for (int c = 0; c < 4; ++c) ((float4*)sW)[c * 128 + tid] = pw[c];
        __syncthreads();
        // prefetch next chunk (retires during compute; consumed next commit)
        if (k0 + 32 < K) { LOAD_F(k0 + 32) LOAD_W(k0 + 32) }

#pragma unroll 4
        for (int kk = 0; kk < 32; ++kk) {
            const float4 f0 = *(const float4*)(&sF[kk][n0]);
            const float4 f1 = *(const float4*)(&sF[kk][n0 + 4]);
            const float4 w0 = *(const float4*)(sW + kk * 64 + d0);
            const float4 w1 = *(const float4*)(sW + kk * 64 + d0 + 4);
            const float fv[8] = { f0.x, f0.y, f0.z, f0.w, f1.x, f1.y, f1.z, f1.w };
            const float wv[8] = { w0.x, w0.y, w0.z, w0.w, w1.x, w1.y, w1.z, w1.w };
#pragma unroll
            for (int j = 0; j < 8; ++j)
#pragma unroll
                for (int i = 0; i < 8; ++i)
                    acc[j][i] = fmaf(fv[j], wv[i], acc[j][i]);
        }
    }
#undef LOAD_F
#undef LOAD_W

    // epilogue: bias (+ReLU), coalesced store
    float bv[8];
    *(float4*)&bv[0] = *(const float4*)(bias + d0);
    *(float4*)&bv[4] = *(const float4*)(bias + d0 + 4);
#pragma unroll
    for (int j = 0; j < 8; ++j) {
        const int gn = bn + n0 + j;
        if (gn < Nn) {
            float o[8];
#pragma unroll
            for (int i = 0; i < 8; ++i) {
                o[i] = acc[j][i] + bv[i];
                if (RELU) o[i] = fmaxf(o[i], 0.f);
            }
            float* yp = Y + (long long)(node0out + gn) * 64 + d0;
            *(float4*)(yp)     = *(float4*)&o[0];
            *(float4*)(yp + 4) = *(float4*)&o[4];
        }
    }
}

// ---------------------------------------------------------------------------
// Bucket pipeline: dst-bucket = dst >> 8 (256 nodes per bucket, NB = 782)
// ---------------------------------------------------------------------------
__global__ void zero_ints(int* __restrict__ p, int n)
{
    int i = blockIdx.x * blockDim.x + threadIdx.x;
    if (i < n) p[i] = 0;
}

__global__ __launch_bounds__(256) void count_kernel(const int* __restrict__ edst,
                                                    int* __restrict__ gcount, int E)
{
    __shared__ int lh[NB];
    for (int i = threadIdx.x; i < NB; i += 256) lh[i] = 0;
    __syncthreads();
    int i  = blockIdx.x * 256 + threadIdx.x;
    int st = gridDim.x * 256;
    for (; i < E; i += st) atomicAdd(&lh[edst[i] >> 8], 1);
    __syncthreads();
    for (int b = threadIdx.x; b < NB; b += 256)
        if (lh[b]) atomicAdd(&gcount[b], lh[b]);
}

// single block, 1024 threads >= NB: exclusive scan of bucket counts
__global__ __launch_bounds__(1024) void scan_kernel(const int* __restrict__ gcount,
                                                    int* __restrict__ bstart,
                                                    int* __restrict__ gcursor, int nb)
{
    const int t = threadIdx.x, lane = t & 63, wid = t >> 6;
    int v = (t < nb) ? gcount[t] : 0;
    int x = v;
#pragma unroll
    for (int o = 1; o < 64; o <<= 1) {
        int y = __shfl_up(x, o, 64);
        if (lane >= o) x += y;
    }
    __shared__ int wsum[16];
    if (lane == 63) wsum[wid] = x;
    __syncthreads();
    if (t == 0) {
        int run = 0;
#pragma unroll
        for (int i = 0; i < 16; ++i) { int s = wsum[i]; wsum[i] = run; run += s; }
    }
    __syncthreads();
    const int excl = x - v + wsum[wid];
    if (t < nb) { bstart[t] = excl; gcursor[t] = excl; }
    if (t == nb - 1) bstart[nb] = excl + v;   // == E
}

// per-block LDS histogram -> one range reservation per touched bucket ->
// grouped writes into ~NB open chunks (L2-resident lines, full-line merges)
__global__ __launch_bounds__(256) void bucket_scatter(const int* __restrict__ esrc,
                                                      const int* __restrict__ edst,
                                                      const float* __restrict__ ew,
                                                      int* __restrict__ gcursor,
                                                      uint2* __restrict__ ebuf, int E)
{
    __shared__ int lh[NB];
    __shared__ int lbase[NB];
    const int G = gridDim.x;
    const long long e0 = (long long)E * blockIdx.x / G;
    const long long e1 = (long long)E * (blockIdx.x + 1) / G;

    for (int i = threadIdx.x; i < NB; i += 256) lh[i] = 0;
    __syncthreads();
    for (long long e = e0 + threadIdx.x; e < e1; e += 256)
        atomicAdd(&lh[edst[e] >> 8], 1);
    __syncthreads();
    for (int b = threadIdx.x; b < NB; b += 256) {
        const int c = lh[b];
        lbase[b] = c ? atomicAdd(&gcursor[b], c) : 0;
    }
    __syncthreads();
    for (int i = threadIdx.x; i < NB; i += 256) lh[i] = 0;   // reuse as local cursor
    __syncthreads();
    for (long long e = e0 + threadIdx.x; e < e1; e += 256) {
        const int dst  = edst[e];
        const int b    = dst >> 8;
        const int off  = atomicAdd(&lh[b], 1);
        const unsigned pack = ((unsigned)(dst & 255) << 18) | (unsigned)esrc[e];
        ebuf[lbase[b] + off] = make_uint2(pack, __float_as_uint(ew[e]));
    }
}

// one block per bucket: accumulate into 64 KB LDS tile (bank-conflict-free
// LDS float atomics), 4-deep unrolled support reads, fused L2-normalize.
__global__ __launch_bounds__(256) void bucket_gather(const float* __restrict__ support,
                                                     const uint2* __restrict__ ebuf,
                                                     const int* __restrict__ bstart,
                                                     float* __restrict__ out)
{
    __shared__ float sAcc[256 * 64];
    const int tid = threadIdx.x, lane = tid & 63, wid = tid >> 6;
    const int b = blockIdx.x;
#pragma unroll
    for (int i = 0; i < 16; ++i)
        *(float4*)(&sAcc[(i * 256 + tid) * 4]) = make_float4(0.f, 0.f, 0.f, 0.f);
    __syncthreads();

    const int start = bstart[b], end = bstart[b + 1];
    for (int base = start + (wid << 2); base < end; base += 16) {
        const int m = end - base;
        if (m >= 4) {
            const uint2 c0 = ebuf[base], c1 = ebuf[base + 1];
            const uint2 c2 = ebuf[base + 2], c3 = ebuf[base + 3];
            const float v0 = support[(long long)(c0.x & 0x3FFFF) * 64 + lane];
            const float v1 = support[(long long)(c1.x & 0x3FFFF) * 64 + lane];
            const float v2 = support[(long long)(c2.x & 0x3FFFF) * 64 + lane];
            const float v3 = support[(long long)(c3.x & 0x3FFFF) * 64 + lane];
            atomicAdd(&sAcc[(c0.x >> 18) * 64 + lane], v0 * __uint_as_float(c0.y));
            atomicAdd(&sAcc[(c1.x >> 18) * 64 + lane], v1 * __uint_as_float(c1.y));
            atomicAdd(&sAcc[(c2.x >> 18) * 64 + lane], v2 * __uint_as_float(c2.y));
            atomicAdd(&sAcc[(c3.x >> 18) * 64 + lane], v3 * __uint_as_float(c3.y));
        } else {
            for (int j = 0; j < m; ++j) {
                const uint2 c = ebuf[base + j];
                const float v = support[(long long)(c.x & 0x3FFFF) * 64 + lane];
                atomicAdd(&sAcc[(c.x >> 18) * 64 + lane], v * __uint_as_float(c.y));
            }
        }
    }
    __syncthreads();

    for (int r = wid; r < 256; r += 4) {
        const int gn = b * 256 + r;
        if (gn < NTOT) {
            const float x = sAcc[r * 64 + lane];
            float ss = x * x;
#pragma unroll
            for (int o = 32; o; o >>= 1) ss += __shfl_xor(ss, o, 64);
            const float nrm = fmaxf(sqrtf(ss), 1e-12f);
            out[(long long)gn * 64 + lane] = x / nrm;
        }
    }
}

// ---------------------------------------------------------------------------
// Fallback path (atomic scatter), only if workspace is too small
// ---------------------------------------------------------------------------
__global__ void zero_kernel(float4* __restrict__ p, long long n4)
{
    long long i  = (long long)blockIdx.x * blockDim.x + threadIdx.x;
    long long st = (long long)gridDim.x * blockDim.x;
    for (; i < n4; i += st) p[i] = float4{0.f, 0.f, 0.f, 0.f};
}

__global__ void scatter_kernel(const float* __restrict__ support,
                               const float* __restrict__ ew,
                               const int* __restrict__ esrc,
                               const int* __restrict__ edst,
                               float* __restrict__ out, int E)
{
    const int d  = threadIdx.x & 63;
    int gw       = blockIdx.x * (blockDim.x >> 6) + (threadIdx.x >> 6);
    const int nw = gridDim.x * (blockDim.x >> 6);
    for (int e = gw; e < E; e += nw) {
        atomicAdd(&out[(long long)edst[e] * 64 + d],
                  support[(long long)esrc[e] * 64 + d] * ew[e]);
    }
}

__global__ void normalize_kernel(float* __restrict__ out, int N)
{
    const int d   = threadIdx.x & 63;
    const int row = blockIdx.x * (blockDim.x >> 6) + (threadIdx.x >> 6);
    if (row < N) {
        const long long base = (long long)row * 64;
        float x  = out[base + d];
        float ss = x * x;
#pragma unroll
        for (int o = 32; o; o >>= 1) ss += __shfl_xor(ss, o, 64);
        out[base + d] = x / fmaxf(sqrtf(ss), 1e-12f);
    }
}

extern "C" void kernel_launch(void* const* d_in, const int* in_sizes, int n_in,
                              void* d_out, int out_size, void* d_ws, size_t ws_size,
                              hipStream_t stream)
{
    const float* feat_a = (const float*)d_in[0];
    const float* W_a    = (const float*)d_in[1];
    const float* b_a    = (const float*)d_in[2];
    const float* feat_b = (const float*)d_in[3];
    const float* W_b    = (const float*)d_in[4];
    const float* b_b    = (const float*)d_in[5];
    const float* feat_c = (const float*)d_in[6];
    const float* W_c    = (const float*)d_in[7];
    const float* b_c    = (const float*)d_in[8];
    const float* gcn_W  = (const float*)d_in[9];
    const float* gcn_b  = (const float*)d_in[10];
    const float* ew     = (const float*)d_in[11];
    const int*   esrc   = (const int*)d_in[12];
    const int*   edst   = (const int*)d_in[13];

    float* out = (float*)d_out;

    // workspace layout
    char* ws = (char*)d_ws;
    const size_t off_support = 0;                                  // 51,200,000 B
    const size_t off_ebuf    = off_support + (size_t)NTOT * D * 4; // 25,600,000 B
    const size_t off_gcount  = off_ebuf + (size_t)NEDGE * 8;
    const size_t off_bstart  = off_gcount + 4096;                  // NB+1 ints
    const size_t off_gcursor = off_bstart + 4096;
    const size_t need        = off_gcursor + 4096;                 // ~76.8 MB

    float* support = (float*)(ws + off_support);

    // encoders: enc = relu(feat @ W + b) -> d_out (dead after gcn reads it)
    gemm128_kernel<512, true ><<<(N_A  + 127) / 128, 128, 0, stream>>>(feat_a, W_a, b_a, out, N_A, 0);
    gemm128_kernel<256, true ><<<(N_B  + 127) / 128, 128, 0, stream>>>(feat_b, W_b, b_b, out, N_B, N_A);
    gemm128_kernel<128, true ><<<(N_C  + 127) / 128, 128, 0, stream>>>(feat_c, W_c, b_c, out, N_C, N_A + N_B);
    // support = enc @ gcn_W + gcn_b
    gemm128_kernel< 64, false><<<(NTOT + 127) / 128, 128, 0, stream>>>(out, gcn_W, gcn_b, support, NTOT, 0);

    if (ws_size >= need) {
        uint2* ebuf    = (uint2*)(ws + off_ebuf);
        int*   gcount  = (int*)(ws + off_gcount);
        int*   bstart  = (int*)(ws + off_bstart);
        int*   gcursor = (int*)(ws + off_gcursor);

        zero_ints<<<(NB + 255) / 256, 256, 0, stream>>>(gcount, NB);
        count_kernel<<<1024, 256, 0, stream>>>(edst, gcount, NEDGE);
        scan_kernel<<<1, 1024, 0, stream>>>(gcount, bstart, gcursor, NB);
        bucket_scatter<<<1024, 256, 0, stream>>>(esrc, edst, ew, gcursor, ebuf, NEDGE);
        bucket_gather<<<NB, 256, 0, stream>>>(support, ebuf, bstart, out);
    } else {
        zero_kernel<<<2048, 256, 0, stream>>>((float4*)out, (long long)NTOT * D / 4);
        scatter_kernel<<<8192, 256, 0, stream>>>(support, ew, esrc, edst, out, NEDGE);
        normalize_kernel<<<NTOT / 4, 256, 0, stream>>>(out, NTOT);
    }
}

// Round 5
// 1056.220 us; speedup vs baseline: 1.9289x; 1.9289x over previous
//
#include <hip/hip_runtime.h>

// Problem constants (from reference)
#define N_A 100000
#define N_B 60000
#define N_C 40000
#define NTOT 200000   // N_A + N_B + N_C
#define NEDGE 3200000
#define D 64

#define SCAN_BLK 1024
#define NB_SCAN ((NTOT + SCAN_BLK - 1) / SCAN_BLK)   // 196

// ---------------------------------------------------------------------------
// GEMM v3: Y[node0out + n] = act(X[n] @ W + b),  X:[Nn][K], W:[K][64]
// Block: 128 threads (2 waves), tile 128 nodes x 64 dims, thread = 8n x 8d.
// K-chunk 32.
//  - Global staging COALESCED: thread t loads float4 at (row = t>>3 + 16p,
//    k = (t&7)*4): lanes 0-7 cover one row's 32 floats = 128 B contiguous.
//  - sF[128][33]: +1-float pad -> compute b32 broadcasts conflict-free
//    (8 distinct rows/instr land in 8 distinct banks).
//  - sW[32][64]: b128 reads are 8-distinct-address broadcasts, 2-way banks.
//  - Register double-buffer: next chunk's feat+W prefetched into VGPRs
//    during compute, committed to LDS after the barrier.
// Inner loop: 64 FMAs per 10 LDS instrs per kk. LDS 24.7 KB -> 6 blocks/CU.
// ---------------------------------------------------------------------------
template <int K, bool RELU>
__global__ __launch_bounds__(128) void gemm128_kernel(
    const float* __restrict__ X, const float* __restrict__ W,
    const float* __restrict__ bias, float* __restrict__ Y,
    int Nn, int node0out)
{
    __shared__ float sF[128][33];   // [n][k] feat chunk, +1 pad
    __shared__ float sW[32 * 64];   // [k][d]

    const int tid  = threadIdx.x;
    const int rql  = tid & 7;        // k-quad: k = rql*4 .. rql*4+3
    const int rowi = tid >> 3;       // 0..15 (row = rowi + 16p)
    const int tn   = tid >> 3;       // n-group: nodes tn*8..tn*8+7
    const int td   = tid & 7;        // d-group: dims td*8..td*8+7
    const int n0   = tn * 8;
    const int d0   = td * 8;
    const int bn   = blockIdx.x * 128;

    float  acc[8][8] = {};           // [n][d]
    float4 pf[8];                    // prefetched feat quads
    float4 pw[4];                    // prefetched W quads

#define LOAD_F(k0_)                                                          \
    _Pragma("unroll")                                                        \
    for (int p = 0; p < 8; ++p) {                                            \
        const int gn = bn + rowi + 16 * p;                                   \
        pf[p] = (gn < Nn)                                                    \
            ? *(const float4*)(X + (long long)gn * K + (k0_) + rql * 4)      \
            : make_float4(0.f, 0.f, 0.f, 0.f);                               \
    }
#define LOAD_W(k0_)                                                          \
    {                                                                        \
        const float4* gw = (const float4*)(W + (long long)(k0_) * 64);       \
        _Pragma("unroll")                                                    \
        for (int c = 0; c < 4; ++c) pw[c] = gw[c * 128 + tid];               \
    }

    LOAD_F(0)
    LOAD_W(0)

    for (int k0 = 0; k0 < K; k0 += 32) {
        __syncthreads();             // previous compute done reading LDS
        // commit staged registers to LDS (scalar stores; pad 33 keeps
        // per-instruction bank aliasing <= 2-way)
#pragma unroll
        for (int p = 0; p < 8; ++p) {
            const int r = rowi + 16 * p;
            sF[r][rql * 4 + 0] = pf[p].x;
            sF[r][rql * 4 + 1] = pf[p].y;
            sF[r][rql * 4 + 2] = pf[p].z;
            sF[r][rql * 4 + 3] = pf[p].w;
        }
#pragma unroll
        for (int c = 0; c < 4; ++c) ((float4*)sW)[c * 128 + tid] = pw[c];
        __syncthreads();
        // prefetch next chunk (retires during the 2048-FMA compute below)
        if (k0 + 32 < K) { LOAD_F(k0 + 32) LOAD_W(k0 + 32) }

#pragma unroll 4
        for (int kk = 0; kk < 32; ++kk) {
            const float4 w0 = *(const float4*)(sW + kk * 64 + d0);
            const float4 w1 = *(const float4*)(sW + kk * 64 + d0 + 4);
            const float wv[8] = { w0.x, w0.y, w0.z, w0.w, w1.x, w1.y, w1.z, w1.w };
            float fv[8];
#pragma unroll
            for (int j = 0; j < 8; ++j) fv[j] = sF[n0 + j][kk];
#pragma unroll
            for (int j = 0; j < 8; ++j)
#pragma unroll
                for (int i = 0; i < 8; ++i)
                    acc[j][i] = fmaf(fv[j], wv[i], acc[j][i]);
        }
    }
#undef LOAD_F
#undef LOAD_W

    // epilogue: bias (+ReLU), coalesced float4 stores
    float bv[8];
    *(float4*)&bv[0] = *(const float4*)(bias + d0);
    *(float4*)&bv[4] = *(const float4*)(bias + d0 + 4);
#pragma unroll
    for (int j = 0; j < 8; ++j) {
        const int gn = bn + n0 + j;
        if (gn < Nn) {
            float o[8];
#pragma unroll
            for (int i = 0; i < 8; ++i) {
                o[i] = acc[j][i] + bv[i];
                if (RELU) o[i] = fmaxf(o[i], 0.f);
            }
            float* yp = Y + (long long)(node0out + gn) * 64 + d0;
            *(float4*)(yp)     = *(float4*)&o[0];
            *(float4*)(yp + 4) = *(float4*)&o[4];
        }
    }
}

// ---------------------------------------------------------------------------
// CSR build (R2 pipeline): zero -> histogram -> 3-pass scan -> cursor fill
// ---------------------------------------------------------------------------
__global__ void zero_ints(int* __restrict__ p, int n)
{
    int i = blockIdx.x * blockDim.x + threadIdx.x;
    if (i < n) p[i] = 0;
}

__global__ void hist_kernel(const int* __restrict__ edst, int* __restrict__ deg, int e)
{
    int i  = blockIdx.x * blockDim.x + threadIdx.x;
    int st = gridDim.x * blockDim.x;
    for (; i < e; i += st) atomicAdd(&deg[edst[i]], 1);
}

__global__ __launch_bounds__(SCAN_BLK) void s1_blocksums(const int* __restrict__ deg,
                                                         int* __restrict__ partials, int n)
{
    const int tid = threadIdx.x;
    const int i   = blockIdx.x * SCAN_BLK + tid;
    int v = (i < n) ? deg[i] : 0;
#pragma unroll
    for (int o = 32; o; o >>= 1) v += __shfl_xor(v, o, 64);
    __shared__ int wsum[SCAN_BLK / 64];
    if ((tid & 63) == 0) wsum[tid >> 6] = v;
    __syncthreads();
    if (tid == 0) {
        int s = 0;
#pragma unroll
        for (int w = 0; w < SCAN_BLK / 64; ++w) s += wsum[w];
        partials[blockIdx.x] = s;
    }
}

__global__ __launch_bounds__(256) void s2_scan(const int* __restrict__ partials,
                                               int* __restrict__ pscan, int np)
{
    __shared__ int arr[512];
    if (threadIdx.x < np) arr[threadIdx.x] = partials[threadIdx.x];
    __syncthreads();
    if (threadIdx.x == 0) {
        int run = 0;
        for (int i = 0; i < np; ++i) { int t = arr[i]; arr[i] = run; run += t; }
    }
    __syncthreads();
    if (threadIdx.x < np) pscan[threadIdx.x] = arr[threadIdx.x];
}

__global__ __launch_bounds__(SCAN_BLK) void s3_scan(const int* __restrict__ deg,
                                                    const int* __restrict__ pscan,
                                                    int* __restrict__ row_start,
                                                    int* __restrict__ cursor, int n)
{
    const int tid  = threadIdx.x;
    const int lane = tid & 63, wid = tid >> 6;
    const int i    = blockIdx.x * SCAN_BLK + tid;
    int v = (i < n) ? deg[i] : 0;
    int x = v;
#pragma unroll
    for (int o = 1; o < 64; o <<= 1) {
        int y = __shfl_up(x, o, 64);
        if (lane >= o) x += y;
    }
    __shared__ int wsum[SCAN_BLK / 64];
    if (lane == 63) wsum[wid] = x;
    __syncthreads();
    if (tid == 0) {
        int run = 0;
#pragma unroll
        for (int w = 0; w < SCAN_BLK / 64; ++w) { int t = wsum[w]; wsum[w] = run; run += t; }
    }
    __syncthreads();
    if (i < n) {
        const int excl = x - v + wsum[wid] + pscan[blockIdx.x];
        row_start[i] = excl;
        cursor[i]    = excl;
    }
}

__global__ void fill_kernel(const int* __restrict__ esrc, const int* __restrict__ edst,
                            const float* __restrict__ ew, int* __restrict__ cursor,
                            uint2* __restrict__ csr, int e)
{
    int i  = blockIdx.x * blockDim.x + threadIdx.x;
    int st = gridDim.x * blockDim.x;
    for (; i < e; i += st) {
        const int t   = edst[i];
        const int pos = atomicAdd(&cursor[t], 1);
        csr[pos] = make_uint2((unsigned)esrc[i], __float_as_uint(ew[i]));
    }
}

// ---------------------------------------------------------------------------
// Pull-based gather + fused L2 normalize: one 64-lane wave per dst node.
// ---------------------------------------------------------------------------
__global__ __launch_bounds__(256) void gather_norm_kernel(const float* __restrict__ support,
                                                          const uint2* __restrict__ csr,
                                                          const int* __restrict__ row_start,
                                                          const int* __restrict__ deg,
                                                          float* __restrict__ out)
{
    const int lane = threadIdx.x & 63;
    const int nid  = blockIdx.x * 4 + (threadIdx.x >> 6);
    if (nid >= NTOT) return;
    const int base = row_start[nid];
    const int dg   = deg[nid];

    float acc = 0.f;
    int i = 0;
    for (; i + 4 <= dg; i += 4) {
        const uint2 c0 = csr[base + i + 0];
        const uint2 c1 = csr[base + i + 1];
        const uint2 c2 = csr[base + i + 2];
        const uint2 c3 = csr[base + i + 3];
        const float v0 = support[(long long)c0.x * D + lane];
        const float v1 = support[(long long)c1.x * D + lane];
        const float v2 = support[(long long)c2.x * D + lane];
        const float v3 = support[(long long)c3.x * D + lane];
        acc = fmaf(v0, __uint_as_float(c0.y), acc);
        acc = fmaf(v1, __uint_as_float(c1.y), acc);
        acc = fmaf(v2, __uint_as_float(c2.y), acc);
        acc = fmaf(v3, __uint_as_float(c3.y), acc);
    }
    for (; i < dg; ++i) {
        const uint2 c = csr[base + i];
        acc = fmaf(support[(long long)c.x * D + lane], __uint_as_float(c.y), acc);
    }

    float ss = acc * acc;
#pragma unroll
    for (int o = 32; o; o >>= 1) ss += __shfl_xor(ss, o, 64);
    const float nrm = fmaxf(sqrtf(ss), 1e-12f);
    out[(long long)nid * D + lane] = acc / nrm;
}

// ---------------------------------------------------------------------------
// Fallback path (atomic scatter), only if workspace is too small
// ---------------------------------------------------------------------------
__global__ void zero_kernel(float4* __restrict__ p, long long n4)
{
    long long i  = (long long)blockIdx.x * blockDim.x + threadIdx.x;
    long long st = (long long)gridDim.x * blockDim.x;
    for (; i < n4; i += st) p[i] = float4{0.f, 0.f, 0.f, 0.f};
}

__global__ void scatter_kernel(const float* __restrict__ support,
                               const float* __restrict__ ew,
                               const int* __restrict__ esrc,
                               const int* __restrict__ edst,
                               float* __restrict__ out, int E)
{
    const int d  = threadIdx.x & 63;
    int gw       = blockIdx.x * (blockDim.x >> 6) + (threadIdx.x >> 6);
    const int nw = gridDim.x * (blockDim.x >> 6);
    for (int e = gw; e < E; e += nw) {
        atomicAdd(&out[(long long)edst[e] * 64 + d],
                  support[(long long)esrc[e] * 64 + d] * ew[e]);
    }
}

__global__ void normalize_kernel(float* __restrict__ out, int N)
{
    const int d   = threadIdx.x & 63;
    const int row = blockIdx.x * (blockDim.x >> 6) + (threadIdx.x >> 6);
    if (row < N) {
        const long long base = (long long)row * 64;
        float x  = out[base + d];
        float ss = x * x;
#pragma unroll
        for (int o = 32; o; o >>= 1) ss += __shfl_xor(ss, o, 64);
        out[base + d] = x / fmaxf(sqrtf(ss), 1e-12f);
    }
}

extern "C" void kernel_launch(void* const* d_in, const int* in_sizes, int n_in,
                              void* d_out, int out_size, void* d_ws, size_t ws_size,
                              hipStream_t stream)
{
    const float* feat_a = (const float*)d_in[0];
    const float* W_a    = (const float*)d_in[1];
    const float* b_a    = (const float*)d_in[2];
    const float* feat_b = (const float*)d_in[3];
    const float* W_b    = (const float*)d_in[4];
    const float* b_b    = (const float*)d_in[5];
    const float* feat_c = (const float*)d_in[6];
    const float* W_c    = (const float*)d_in[7];
    const float* b_c    = (const float*)d_in[8];
    const float* gcn_W  = (const float*)d_in[9];
    const float* gcn_b  = (const float*)d_in[10];
    const float* ew     = (const float*)d_in[11];
    const int*   esrc   = (const int*)d_in[12];
    const int*   edst   = (const int*)d_in[13];

    float* out = (float*)d_out;

    // workspace layout (R2)
    char* ws = (char*)d_ws;
    const size_t off_support = 0;                               // 51,200,000 B
    const size_t off_deg     = off_support + (size_t)NTOT * D * 4;
    const size_t off_rowst   = off_deg   + (size_t)NTOT * 4;
    const size_t off_cursor  = off_rowst + (size_t)NTOT * 4;
    const size_t off_part    = off_cursor + (size_t)NTOT * 4;
    const size_t off_pscan   = off_part  + 1024;
    const size_t off_csr     = off_pscan + 1024;
    const size_t need        = off_csr + (size_t)NEDGE * 8;     // ~79.2 MB

    float* support = (float*)(ws + off_support);

    // encoders: enc = relu(feat @ W + b) -> d_out (dead after gcn reads it)
    gemm128_kernel<512, true ><<<(N_A  + 127) / 128, 128, 0, stream>>>(feat_a, W_a, b_a, out, N_A, 0);
    gemm128_kernel<256, true ><<<(N_B  + 127) / 128, 128, 0, stream>>>(feat_b, W_b, b_b, out, N_B, N_A);
    gemm128_kernel<128, true ><<<(N_C  + 127) / 128, 128, 0, stream>>>(feat_c, W_c, b_c, out, N_C, N_A + N_B);
    // support = enc @ gcn_W + gcn_b
    gemm128_kernel< 64, false><<<(NTOT + 127) / 128, 128, 0, stream>>>(out, gcn_W, gcn_b, support, NTOT, 0);

    if (ws_size >= need) {
        int*   deg     = (int*)(ws + off_deg);
        int*   rowst   = (int*)(ws + off_rowst);
        int*   cursor  = (int*)(ws + off_cursor);
        int*   part    = (int*)(ws + off_part);
        int*   pscan   = (int*)(ws + off_pscan);
        uint2* csr     = (uint2*)(ws + off_csr);

        zero_ints<<<(NTOT + 255) / 256, 256, 0, stream>>>(deg, NTOT);
        hist_kernel<<<4096, 256, 0, stream>>>(edst, deg, NEDGE);
        s1_blocksums<<<NB_SCAN, SCAN_BLK, 0, stream>>>(deg, part, NTOT);
        s2_scan<<<1, 256, 0, stream>>>(part, pscan, NB_SCAN);
        s3_scan<<<NB_SCAN, SCAN_BLK, 0, stream>>>(deg, pscan, rowst, cursor, NTOT);
        fill_kernel<<<4096, 256, 0, stream>>>(esrc, edst, ew, cursor, csr, NEDGE);

        gather_norm_kernel<<<(NTOT + 3) / 4, 256, 0, stream>>>(support, csr, rowst, deg, out);
    } else {
        zero_kernel<<<2048, 256, 0, stream>>>((float4*)out, (long long)NTOT * D / 4);
        scatter_kernel<<<8192, 256, 0, stream>>>(support, ew, esrc, edst, out, NEDGE);
        normalize_kernel<<<NTOT / 4, 256, 0, stream>>>(out, NTOT);
    }
}